// Round 4
// baseline (364.097 us; speedup 1.0000x reference)
//
#include <hip/hip_runtime.h>

#define D 128

typedef float f2v __attribute__((ext_vector_type(2)));

// ---------------- precompute: CSR build with ONE atomic per edge ----------------

__global__ __launch_bounds__(256) void k_init(int* __restrict__ cnt, int n) {
  int i = blockIdx.x * 256 + threadIdx.x;
  if (i < n) cnt[i] = 0;
}

// fused histogram + within-row rank: one int atomic per edge
__global__ __launch_bounds__(256) void k_rank(const int* __restrict__ dst, int* __restrict__ cnt,
                                              int* __restrict__ p_local, int E) {
  int e = blockIdx.x * 256 + threadIdx.x;
  if (e < E) p_local[e] = atomicAdd(&cnt[dst[e]], 1);
}

// scan pass A: per-block (256 elems) sums
__global__ __launch_bounds__(256) void k_blocksum(const int* __restrict__ cnt, int* __restrict__ bsum, int n) {
  int i = blockIdx.x * 256 + threadIdx.x;
  int v = (i < n) ? cnt[i] : 0;
#pragma unroll
  for (int off = 32; off > 0; off >>= 1) v += __shfl_down(v, off);
  __shared__ int ws[4];
  if ((threadIdx.x & 63) == 0) ws[threadIdx.x >> 6] = v;
  __syncthreads();
  if (threadIdx.x == 0) bsum[blockIdx.x] = ws[0] + ws[1] + ws[2] + ws[3];
}

// scan pass B: exclusive scan of block sums (nb <= 256), single block
__global__ __launch_bounds__(256) void k_scanb(const int* __restrict__ bsum, int* __restrict__ boff, int nb) {
  __shared__ int s[256];
  int t = threadIdx.x;
  int v = (t < nb) ? bsum[t] : 0;
  s[t] = v;
  __syncthreads();
#pragma unroll
  for (int off = 1; off < 256; off <<= 1) {
    int u = (t >= off) ? s[t - off] : 0;
    __syncthreads();
    s[t] += u;
    __syncthreads();
  }
  if (t < nb) boff[t] = s[t] - v;  // exclusive
}

// scan pass C: block-local exclusive scan + global offset -> rowptr
__global__ __launch_bounds__(256) void k_scanc(const int* __restrict__ cnt, const int* __restrict__ boff,
                                               int* __restrict__ rowptr, int n, int Etot) {
  __shared__ int s[256];
  int t = threadIdx.x;
  int i = blockIdx.x * 256 + t;
  int v = (i < n) ? cnt[i] : 0;
  s[t] = v;
  __syncthreads();
#pragma unroll
  for (int off = 1; off < 256; off <<= 1) {
    int u = (t >= off) ? s[t - off] : 0;
    __syncthreads();
    s[t] += u;
    __syncthreads();
  }
  int ex = s[t] - v + boff[blockIdx.x];
  if (i < n) rowptr[i] = ex;
  if (i == 0) rowptr[n] = Etot;
}

// atomic-free scatter: pos = rowptr[dst] + p_local ; csr = {src_bits, ew}
__global__ __launch_bounds__(256) void k_scatter(const int* __restrict__ src, const int* __restrict__ dst,
                                                 const float* __restrict__ ew, const int* __restrict__ rowptr,
                                                 const int* __restrict__ p_local, float2* __restrict__ csr, int E) {
  int e = blockIdx.x * 256 + threadIdx.x;
  if (e < E) {
    int d = dst[e];
    int pos = rowptr[d] + p_local[e];
    float2 rec;
    rec.x = __int_as_float(src[e]);
    rec.y = ew[e];
    csr[pos] = rec;
  }
}

// wave per node: deg = 1 + sum(ew over row); dis = rsqrt(deg)
__global__ __launch_bounds__(256) void k_degdis(const float2* __restrict__ csr, const int* __restrict__ rowptr,
                                                float* __restrict__ dis, int n) {
  int node = blockIdx.x * 4 + (threadIdx.x >> 6);
  if (node >= n) return;
  int lane = threadIdx.x & 63;
  int beg = rowptr[node], end = rowptr[node + 1];
  float s = 0.f;
  for (int e = beg + lane; e < end; e += 64) s += csr[e].y;
#pragma unroll
  for (int off = 32; off > 0; off >>= 1) s += __shfl_down(s, off);
  if (lane == 0) {
    float dg = 1.0f + s;
    dis[node] = dg > 0.f ? rsqrtf(dg) : 0.f;
  }
}

// fold dis[src] into csr.y (dis[dst] is applied per-node inside k_agg)
__global__ __launch_bounds__(256) void k_norm(float2* __restrict__ csr, const float* __restrict__ dis, int E) {
  int e = blockIdx.x * 256 + threadIdx.x;
  if (e < E) {
    float2 rec = csr[e];
    rec.y *= dis[__float_as_int(rec.x)];
    csr[e] = rec;
  }
}

// ---------------- per-layer: GEMM (h = z @ W), f32 ----------------
// block = 256 threads, tile 32 rows x 128 cols; per-thread 4 rows x 4 cols.
// z tile in LDS (broadcast reads, conflict-free); W streamed float4 (L2-hot).

__global__ __launch_bounds__(256) void k_gemm(const float* __restrict__ Z, const float* __restrict__ W,
                                              float* __restrict__ H, int n) {
  __shared__ float zs[32 * 128];
  int tid = threadIdx.x;
  int row0 = blockIdx.x * 32;
  const float4* zg = (const float4*)Z;
  float4* zs4 = (float4*)zs;
#pragma unroll
  for (int i = 0; i < 4; ++i) {
    int idx = tid + 256 * i;               // float4 index within tile [0,1024)
    int r = row0 + (idx >> 5);             // 32 float4 per row
    float4 v = make_float4(0.f, 0.f, 0.f, 0.f);
    if (r < n) v = zg[(size_t)row0 * 32 + idx];
    zs4[idx] = v;
  }
  __syncthreads();
  int c4 = tid & 31;   // cols [4*c4, 4*c4+4)
  int r4 = tid >> 5;   // rows [4*r4, 4*r4+4) within tile
  const float4* W4 = (const float4*)W;
  float4 acc[4];
#pragma unroll
  for (int i = 0; i < 4; ++i) acc[i] = make_float4(0.f, 0.f, 0.f, 0.f);
#pragma unroll 2
  for (int k = 0; k < 128; k += 4) {
    float4 w[4];
#pragma unroll
    for (int j = 0; j < 4; ++j) w[j] = W4[(size_t)(k + j) * 32 + c4];
#pragma unroll
    for (int i = 0; i < 4; ++i) {
      float4 z4 = *(const float4*)&zs[(r4 * 4 + i) * 128 + k];
#pragma unroll
      for (int j = 0; j < 4; ++j) {
        float zj = (j == 0) ? z4.x : (j == 1) ? z4.y : (j == 2) ? z4.z : z4.w;
        acc[i].x = fmaf(zj, w[j].x, acc[i].x);
        acc[i].y = fmaf(zj, w[j].y, acc[i].y);
        acc[i].z = fmaf(zj, w[j].z, acc[i].z);
        acc[i].w = fmaf(zj, w[j].w, acc[i].w);
      }
    }
  }
  float4* H4 = (float4*)H;
#pragma unroll
  for (int i = 0; i < 4; ++i) {
    int r = row0 + r4 * 4 + i;
    if (r < n) H4[(size_t)r * 32 + c4] = acc[i];
  }
}

// ---------------- per-layer: aggregation + bias + relu ----------------
// one 64-lane wave per node; lane holds float2 (2 features); 4-edge unroll.
// out = dis[n] * sum_e (dis[src]*ew)*h[src]  +  dis[n]^2 * h[n]  + b, relu

__global__ __launch_bounds__(256) void k_agg(const float* __restrict__ H, const int* __restrict__ rowptr,
                                             const float2* __restrict__ csr, const float* __restrict__ dis,
                                             const float* __restrict__ bias, float* __restrict__ out, int n) {
  int node = blockIdx.x * 4 + (threadIdx.x >> 6);
  if (node >= n) return;
  int lane = threadIdx.x & 63;
  const float2* h2 = (const float2*)H;
  float ax = 0.f, ay = 0.f;
  int e = rowptr[node];
  const int end = rowptr[node + 1];
  for (; e + 4 <= end; e += 4) {
    float2 r0 = csr[e];
    float2 r1 = csr[e + 1];
    float2 r2 = csr[e + 2];
    float2 r3 = csr[e + 3];
    float2 g0 = h2[(size_t)__float_as_int(r0.x) * 64 + lane];
    float2 g1 = h2[(size_t)__float_as_int(r1.x) * 64 + lane];
    float2 g2 = h2[(size_t)__float_as_int(r2.x) * 64 + lane];
    float2 g3 = h2[(size_t)__float_as_int(r3.x) * 64 + lane];
    ax = fmaf(g0.x, r0.y, ax); ay = fmaf(g0.y, r0.y, ay);
    ax = fmaf(g1.x, r1.y, ax); ay = fmaf(g1.y, r1.y, ay);
    ax = fmaf(g2.x, r2.y, ax); ay = fmaf(g2.y, r2.y, ay);
    ax = fmaf(g3.x, r3.y, ax); ay = fmaf(g3.y, r3.y, ay);
  }
  for (; e < end; ++e) {
    float2 r0 = csr[e];
    float2 g0 = h2[(size_t)__float_as_int(r0.x) * 64 + lane];
    ax = fmaf(g0.x, r0.y, ax); ay = fmaf(g0.y, r0.y, ay);
  }
  float dn = dis[node];
  float sn = dn * dn;
  float2 hv = h2[(size_t)node * 64 + lane];
  float2 bv = ((const float2*)bias)[lane];
  f2v o;
  o.x = fmaxf(fmaf(dn, ax, fmaf(sn, hv.x, bv.x)), 0.f);
  o.y = fmaxf(fmaf(dn, ay, fmaf(sn, hv.y, bv.y)), 0.f);
  __builtin_nontemporal_store(o, (f2v*)out + (size_t)node * 64 + lane);
}

// ---------------- host ----------------

extern "C" void kernel_launch(void* const* d_in, const int* in_sizes, int n_in,
                              void* d_out, int out_size, void* d_ws, size_t ws_size,
                              hipStream_t stream) {
  const float* x  = (const float*)d_in[0];
  const int*   ei = (const int*)d_in[1];   // int32: [2, E] row-major
  const float* ew = (const float*)d_in[2];
  const float* Wl[3] = {(const float*)d_in[3], (const float*)d_in[5], (const float*)d_in[7]};
  const float* bl[3] = {(const float*)d_in[4], (const float*)d_in[6], (const float*)d_in[8]};

  const int n = in_sizes[0] / D;
  const int E = in_sizes[1] / 2;
  const int* src = ei;
  const int* dst = ei + E;

  char* p = (char*)d_ws;
  float*  Z       = (float*)p;  p += (size_t)n * D * 4;
  float*  H       = (float*)p;  p += (size_t)n * D * 4;
  float*  dis     = (float*)p;  p += (size_t)n * 4;
  int*    cnt     = (int*)p;    p += (size_t)n * 4;
  int*    rowptr  = (int*)p;    p += (size_t)(n + 1) * 4;
  int*    bsum    = (int*)p;    p += 256 * 4;
  int*    boff    = (int*)p;    p += 256 * 4;
  int*    p_local = (int*)p;    p += (size_t)E * 4;
  float2* csr     = (float2*)p; p += (size_t)E * 8;
  (void)ws_size; (void)n_in;

  const int gb = (n + 255) / 256;   // blocks over nodes
  const int ge = (E + 255) / 256;   // blocks over edges

  k_init<<<gb, 256, 0, stream>>>(cnt, n);
  k_rank<<<ge, 256, 0, stream>>>(dst, cnt, p_local, E);
  k_blocksum<<<gb, 256, 0, stream>>>(cnt, bsum, n);
  k_scanb<<<1, 256, 0, stream>>>(bsum, boff, gb);
  k_scanc<<<gb, 256, 0, stream>>>(cnt, boff, rowptr, n, E);
  k_scatter<<<ge, 256, 0, stream>>>(src, dst, ew, rowptr, p_local, csr, E);
  k_degdis<<<(n + 3) / 4, 256, 0, stream>>>(csr, rowptr, dis, n);
  k_norm<<<ge, 256, 0, stream>>>(csr, dis, E);

  const float* zin = x;
  float* outp = (float*)d_out;
  for (int l = 0; l < 3; ++l) {
    k_gemm<<<(n + 31) / 32, 256, 0, stream>>>(zin, Wl[l], H, n);
    float* zo = (l == 2) ? outp : Z;
    k_agg<<<(n + 3) / 4, 256, 0, stream>>>(H, rowptr, csr, dis, bl[l], zo, n);
    zin = Z;
  }
}

// Round 5
// 284.608 us; speedup vs baseline: 1.2793x; 1.2793x over previous
//
#include <hip/hip_runtime.h>

#define D 128

typedef float f2v __attribute__((ext_vector_type(2)));

// bf16 round-to-nearest-even (no NaN handling needed here)
__device__ __forceinline__ unsigned bf16r(float f) {
  unsigned u = __float_as_uint(f);
  return (u + 0x7fffu + ((u >> 16) & 1u)) >> 16;
}

// ---------------- precompute: CSR build with ONE atomic per edge ----------------

__global__ __launch_bounds__(256) void k_init(int* __restrict__ cnt, int n) {
  int i = blockIdx.x * 256 + threadIdx.x;
  if (i < n) cnt[i] = 0;
}

// fused histogram + within-row rank: one int atomic per edge
__global__ __launch_bounds__(256) void k_rank(const int* __restrict__ dst, int* __restrict__ cnt,
                                              int* __restrict__ p_local, int E) {
  int e = blockIdx.x * 256 + threadIdx.x;
  if (e < E) p_local[e] = atomicAdd(&cnt[dst[e]], 1);
}

// scan pass A: per-block (256 elems) sums
__global__ __launch_bounds__(256) void k_blocksum(const int* __restrict__ cnt, int* __restrict__ bsum, int n) {
  int i = blockIdx.x * 256 + threadIdx.x;
  int v = (i < n) ? cnt[i] : 0;
#pragma unroll
  for (int off = 32; off > 0; off >>= 1) v += __shfl_down(v, off);
  __shared__ int ws[4];
  if ((threadIdx.x & 63) == 0) ws[threadIdx.x >> 6] = v;
  __syncthreads();
  if (threadIdx.x == 0) bsum[blockIdx.x] = ws[0] + ws[1] + ws[2] + ws[3];
}

// scan pass B: exclusive scan of block sums (nb <= 256), single block
__global__ __launch_bounds__(256) void k_scanb(const int* __restrict__ bsum, int* __restrict__ boff, int nb) {
  __shared__ int s[256];
  int t = threadIdx.x;
  int v = (t < nb) ? bsum[t] : 0;
  s[t] = v;
  __syncthreads();
#pragma unroll
  for (int off = 1; off < 256; off <<= 1) {
    int u = (t >= off) ? s[t - off] : 0;
    __syncthreads();
    s[t] += u;
    __syncthreads();
  }
  if (t < nb) boff[t] = s[t] - v;  // exclusive
}

// scan pass C: block-local exclusive scan + global offset -> rowptr
__global__ __launch_bounds__(256) void k_scanc(const int* __restrict__ cnt, const int* __restrict__ boff,
                                               int* __restrict__ rowptr, int n, int Etot) {
  __shared__ int s[256];
  int t = threadIdx.x;
  int i = blockIdx.x * 256 + t;
  int v = (i < n) ? cnt[i] : 0;
  s[t] = v;
  __syncthreads();
#pragma unroll
  for (int off = 1; off < 256; off <<= 1) {
    int u = (t >= off) ? s[t - off] : 0;
    __syncthreads();
    s[t] += u;
    __syncthreads();
  }
  int ex = s[t] - v + boff[blockIdx.x];
  if (i < n) rowptr[i] = ex;
  if (i == 0) rowptr[n] = Etot;
}

// atomic-free scatter: pos = rowptr[dst] + p_local ; csr = {src_bits, ew}
__global__ __launch_bounds__(256) void k_scatter(const int* __restrict__ src, const int* __restrict__ dst,
                                                 const float* __restrict__ ew, const int* __restrict__ rowptr,
                                                 const int* __restrict__ p_local, float2* __restrict__ csr, int E) {
  int e = blockIdx.x * 256 + threadIdx.x;
  if (e < E) {
    int d = dst[e];
    int pos = rowptr[d] + p_local[e];
    float2 rec;
    rec.x = __int_as_float(src[e]);
    rec.y = ew[e];
    csr[pos] = rec;
  }
}

// wave per node: deg = 1 + sum(ew over row); dis = rsqrt(deg)
__global__ __launch_bounds__(256) void k_degdis(const float2* __restrict__ csr, const int* __restrict__ rowptr,
                                                float* __restrict__ dis, int n) {
  int node = blockIdx.x * 4 + (threadIdx.x >> 6);
  if (node >= n) return;
  int lane = threadIdx.x & 63;
  int beg = rowptr[node], end = rowptr[node + 1];
  float s = 0.f;
  for (int e = beg + lane; e < end; e += 64) s += csr[e].y;
#pragma unroll
  for (int off = 32; off > 0; off >>= 1) s += __shfl_down(s, off);
  if (lane == 0) {
    float dg = 1.0f + s;
    dis[node] = dg > 0.f ? rsqrtf(dg) : 0.f;
  }
}

// fold dis[src] into csr.y (dis[dst] is applied per-node inside k_agg)
__global__ __launch_bounds__(256) void k_norm(float2* __restrict__ csr, const float* __restrict__ dis, int E) {
  int e = blockIdx.x * 256 + threadIdx.x;
  if (e < E) {
    float2 rec = csr[e];
    rec.y *= dis[__float_as_int(rec.x)];
    csr[e] = rec;
  }
}

// ---------------- per-layer: GEMM (h = z @ W), f32 compute, bf16 store ----------------
// block = 256 threads, tile 32 rows x 128 cols; per-thread 4 rows x 4 cols.

__global__ __launch_bounds__(256) void k_gemm(const float* __restrict__ Z, const float* __restrict__ W,
                                              unsigned short* __restrict__ H, int n) {
  __shared__ float zs[32 * 128];
  int tid = threadIdx.x;
  int row0 = blockIdx.x * 32;
  const float4* zg = (const float4*)Z;
  float4* zs4 = (float4*)zs;
#pragma unroll
  for (int i = 0; i < 4; ++i) {
    int idx = tid + 256 * i;               // float4 index within tile [0,1024)
    int r = row0 + (idx >> 5);             // 32 float4 per row
    float4 v = make_float4(0.f, 0.f, 0.f, 0.f);
    if (r < n) v = zg[(size_t)row0 * 32 + idx];
    zs4[idx] = v;
  }
  __syncthreads();
  int c4 = tid & 31;   // cols [4*c4, 4*c4+4)
  int r4 = tid >> 5;   // rows [4*r4, 4*r4+4) within tile
  const float4* W4 = (const float4*)W;
  float4 acc[4];
#pragma unroll
  for (int i = 0; i < 4; ++i) acc[i] = make_float4(0.f, 0.f, 0.f, 0.f);
#pragma unroll 2
  for (int k = 0; k < 128; k += 4) {
    float4 w[4];
#pragma unroll
    for (int j = 0; j < 4; ++j) w[j] = W4[(size_t)(k + j) * 32 + c4];
#pragma unroll
    for (int i = 0; i < 4; ++i) {
      float4 z4 = *(const float4*)&zs[(r4 * 4 + i) * 128 + k];
#pragma unroll
      for (int j = 0; j < 4; ++j) {
        float zj = (j == 0) ? z4.x : (j == 1) ? z4.y : (j == 2) ? z4.z : z4.w;
        acc[i].x = fmaf(zj, w[j].x, acc[i].x);
        acc[i].y = fmaf(zj, w[j].y, acc[i].y);
        acc[i].z = fmaf(zj, w[j].z, acc[i].z);
        acc[i].w = fmaf(zj, w[j].w, acc[i].w);
      }
    }
  }
  uint2* H2 = (uint2*)H;  // 2 dwords = 4 bf16 cols
#pragma unroll
  for (int i = 0; i < 4; ++i) {
    int r = row0 + r4 * 4 + i;
    if (r < n) {
      uint2 o;
      o.x = bf16r(acc[i].x) | (bf16r(acc[i].y) << 16);
      o.y = bf16r(acc[i].z) | (bf16r(acc[i].w) << 16);
      H2[(size_t)r * 32 + c4] = o;
    }
  }
}

// ---------------- per-layer: aggregation + bias + relu ----------------
// one 64-lane wave per node; lane holds 1 dword = 2 bf16 features; 4-edge unroll.
// out = dis[n] * sum_e (dis[src]*ew)*h[src]  +  dis[n]^2 * h[n]  + b, relu

__global__ __launch_bounds__(256) void k_agg(const unsigned* __restrict__ Hb, const int* __restrict__ rowptr,
                                             const float2* __restrict__ csr, const float* __restrict__ dis,
                                             const float* __restrict__ bias, float* __restrict__ out, int n) {
  int node = __builtin_amdgcn_readfirstlane(blockIdx.x * 4 + (threadIdx.x >> 6));
  if (node >= n) return;
  int lane = threadIdx.x & 63;
  float ax = 0.f, ay = 0.f;
  int e = rowptr[node];
  const int end = rowptr[node + 1];
  for (; e + 4 <= end; e += 4) {
    float2 r0 = csr[e];
    float2 r1 = csr[e + 1];
    float2 r2 = csr[e + 2];
    float2 r3 = csr[e + 3];
    unsigned g0 = Hb[(size_t)__float_as_int(r0.x) * 64 + lane];
    unsigned g1 = Hb[(size_t)__float_as_int(r1.x) * 64 + lane];
    unsigned g2 = Hb[(size_t)__float_as_int(r2.x) * 64 + lane];
    unsigned g3 = Hb[(size_t)__float_as_int(r3.x) * 64 + lane];
    ax = fmaf(__uint_as_float(g0 << 16), r0.y, ax); ay = fmaf(__uint_as_float(g0 & 0xffff0000u), r0.y, ay);
    ax = fmaf(__uint_as_float(g1 << 16), r1.y, ax); ay = fmaf(__uint_as_float(g1 & 0xffff0000u), r1.y, ay);
    ax = fmaf(__uint_as_float(g2 << 16), r2.y, ax); ay = fmaf(__uint_as_float(g2 & 0xffff0000u), r2.y, ay);
    ax = fmaf(__uint_as_float(g3 << 16), r3.y, ax); ay = fmaf(__uint_as_float(g3 & 0xffff0000u), r3.y, ay);
  }
  for (; e < end; ++e) {
    float2 r0 = csr[e];
    unsigned g0 = Hb[(size_t)__float_as_int(r0.x) * 64 + lane];
    ax = fmaf(__uint_as_float(g0 << 16), r0.y, ax); ay = fmaf(__uint_as_float(g0 & 0xffff0000u), r0.y, ay);
  }
  float dn = dis[node];
  float sn = dn * dn;
  unsigned hv = Hb[(size_t)node * 64 + lane];
  float hvx = __uint_as_float(hv << 16);
  float hvy = __uint_as_float(hv & 0xffff0000u);
  float2 bv = ((const float2*)bias)[lane];
  f2v o;
  o.x = fmaxf(fmaf(dn, ax, fmaf(sn, hvx, bv.x)), 0.f);
  o.y = fmaxf(fmaf(dn, ay, fmaf(sn, hvy, bv.y)), 0.f);
  __builtin_nontemporal_store(o, (f2v*)out + (size_t)node * 64 + lane);
}

// ---------------- host ----------------

extern "C" void kernel_launch(void* const* d_in, const int* in_sizes, int n_in,
                              void* d_out, int out_size, void* d_ws, size_t ws_size,
                              hipStream_t stream) {
  const float* x  = (const float*)d_in[0];
  const int*   ei = (const int*)d_in[1];   // int32: [2, E] row-major
  const float* ew = (const float*)d_in[2];
  const float* Wl[3] = {(const float*)d_in[3], (const float*)d_in[5], (const float*)d_in[7]};
  const float* bl[3] = {(const float*)d_in[4], (const float*)d_in[6], (const float*)d_in[8]};

  const int n = in_sizes[0] / D;
  const int E = in_sizes[1] / 2;
  const int* src = ei;
  const int* dst = ei + E;

  char* p = (char*)d_ws;
  float*          Z       = (float*)p;          p += (size_t)n * D * 4;
  unsigned short* H       = (unsigned short*)p; p += (size_t)n * D * 2;
  float*          dis     = (float*)p;          p += (size_t)n * 4;
  int*            cnt     = (int*)p;            p += (size_t)n * 4;
  int*            rowptr  = (int*)p;            p += (size_t)(n + 1) * 4;
  int*            bsum    = (int*)p;            p += 256 * 4;
  int*            boff    = (int*)p;            p += 256 * 4;
  int*            p_local = (int*)p;            p += (size_t)E * 4;
  float2*         csr     = (float2*)p;         p += (size_t)E * 8;
  (void)ws_size; (void)n_in;

  const int gb = (n + 255) / 256;   // blocks over nodes
  const int ge = (E + 255) / 256;   // blocks over edges

  k_init<<<gb, 256, 0, stream>>>(cnt, n);
  k_rank<<<ge, 256, 0, stream>>>(dst, cnt, p_local, E);
  k_blocksum<<<gb, 256, 0, stream>>>(cnt, bsum, n);
  k_scanb<<<1, 256, 0, stream>>>(bsum, boff, gb);
  k_scanc<<<gb, 256, 0, stream>>>(cnt, boff, rowptr, n, E);
  k_scatter<<<ge, 256, 0, stream>>>(src, dst, ew, rowptr, p_local, csr, E);
  k_degdis<<<(n + 3) / 4, 256, 0, stream>>>(csr, rowptr, dis, n);
  k_norm<<<ge, 256, 0, stream>>>(csr, dis, E);

  const float* zin = x;
  float* outp = (float*)d_out;
  for (int l = 0; l < 3; ++l) {
    k_gemm<<<(n + 31) / 32, 256, 0, stream>>>(zin, Wl[l], H, n);
    float* zo = (l == 2) ? outp : Z;
    k_agg<<<(n + 3) / 4, 256, 0, stream>>>((const unsigned*)H, rowptr, csr, dis, bl[l], zo, n);
    zin = Z;
  }
}

// Round 6
// 257.776 us; speedup vs baseline: 1.4125x; 1.1041x over previous
//
#include <hip/hip_runtime.h>

#define D 128

typedef float f2v __attribute__((ext_vector_type(2)));
typedef short bf16x8 __attribute__((ext_vector_type(8)));
typedef float f32x4 __attribute__((ext_vector_type(4)));

// bf16 round-to-nearest-even
__device__ __forceinline__ unsigned bf16r(float f) {
  unsigned u = __float_as_uint(f);
  return (u + 0x7fffu + ((u >> 16) & 1u)) >> 16;
}

// ---------------- precompute: CSR build with ONE atomic per edge ----------------

__global__ __launch_bounds__(256) void k_init(int* __restrict__ cnt, int n) {
  int i = blockIdx.x * 256 + threadIdx.x;
  if (i < n) cnt[i] = 0;
}

__global__ __launch_bounds__(256) void k_rank(const int* __restrict__ dst, int* __restrict__ cnt,
                                              int* __restrict__ p_local, int E) {
  int e = blockIdx.x * 256 + threadIdx.x;
  if (e < E) p_local[e] = atomicAdd(&cnt[dst[e]], 1);
}

__global__ __launch_bounds__(256) void k_blocksum(const int* __restrict__ cnt, int* __restrict__ bsum, int n) {
  int i = blockIdx.x * 256 + threadIdx.x;
  int v = (i < n) ? cnt[i] : 0;
#pragma unroll
  for (int off = 32; off > 0; off >>= 1) v += __shfl_down(v, off);
  __shared__ int ws[4];
  if ((threadIdx.x & 63) == 0) ws[threadIdx.x >> 6] = v;
  __syncthreads();
  if (threadIdx.x == 0) bsum[blockIdx.x] = ws[0] + ws[1] + ws[2] + ws[3];
}

__global__ __launch_bounds__(256) void k_scanb(const int* __restrict__ bsum, int* __restrict__ boff, int nb) {
  __shared__ int s[256];
  int t = threadIdx.x;
  int v = (t < nb) ? bsum[t] : 0;
  s[t] = v;
  __syncthreads();
#pragma unroll
  for (int off = 1; off < 256; off <<= 1) {
    int u = (t >= off) ? s[t - off] : 0;
    __syncthreads();
    s[t] += u;
    __syncthreads();
  }
  if (t < nb) boff[t] = s[t] - v;  // exclusive
}

__global__ __launch_bounds__(256) void k_scanc(const int* __restrict__ cnt, const int* __restrict__ boff,
                                               int* __restrict__ rowptr, int n, int Etot) {
  __shared__ int s[256];
  int t = threadIdx.x;
  int i = blockIdx.x * 256 + t;
  int v = (i < n) ? cnt[i] : 0;
  s[t] = v;
  __syncthreads();
#pragma unroll
  for (int off = 1; off < 256; off <<= 1) {
    int u = (t >= off) ? s[t - off] : 0;
    __syncthreads();
    s[t] += u;
    __syncthreads();
  }
  int ex = s[t] - v + boff[blockIdx.x];
  if (i < n) rowptr[i] = ex;
  if (i == 0) rowptr[n] = Etot;
}

__global__ __launch_bounds__(256) void k_scatter(const int* __restrict__ src, const int* __restrict__ dst,
                                                 const float* __restrict__ ew, const int* __restrict__ rowptr,
                                                 const int* __restrict__ p_local, float2* __restrict__ csr, int E) {
  int e = blockIdx.x * 256 + threadIdx.x;
  if (e < E) {
    int d = dst[e];
    int pos = rowptr[d] + p_local[e];
    float2 rec;
    rec.x = __int_as_float(src[e]);
    rec.y = ew[e];
    csr[pos] = rec;
  }
}

__global__ __launch_bounds__(256) void k_degdis(const float2* __restrict__ csr, const int* __restrict__ rowptr,
                                                float* __restrict__ dis, int n) {
  int node = blockIdx.x * 4 + (threadIdx.x >> 6);
  if (node >= n) return;
  int lane = threadIdx.x & 63;
  int beg = rowptr[node], end = rowptr[node + 1];
  float s = 0.f;
  for (int e = beg + lane; e < end; e += 64) s += csr[e].y;
#pragma unroll
  for (int off = 32; off > 0; off >>= 1) s += __shfl_down(s, off);
  if (lane == 0) {
    float dg = 1.0f + s;
    dis[node] = dg > 0.f ? rsqrtf(dg) : 0.f;
  }
}

__global__ __launch_bounds__(256) void k_norm(float2* __restrict__ csr, const float* __restrict__ dis, int E) {
  int e = blockIdx.x * 256 + threadIdx.x;
  if (e < E) {
    float2 rec = csr[e];
    rec.y *= dis[__float_as_int(rec.x)];
    csr[e] = rec;
  }
}

// ---------------- converts ----------------

// f32 -> bf16, 4 elems/thread
__global__ __launch_bounds__(256) void k_cvt(const float* __restrict__ X, unsigned short* __restrict__ Xb, int total4) {
  int i = blockIdx.x * 256 + threadIdx.x;
  if (i < total4) {
    float4 v = ((const float4*)X)[i];
    ushort4 o;
    o.x = (unsigned short)bf16r(v.x);
    o.y = (unsigned short)bf16r(v.y);
    o.z = (unsigned short)bf16r(v.z);
    o.w = (unsigned short)bf16r(v.w);
    ((ushort4*)Xb)[i] = o;
  }
}

// all 3 weights: f32 [k][n] -> bf16 transposed [n][k]
__global__ __launch_bounds__(256) void k_cvtw(const float* __restrict__ W0, const float* __restrict__ W1,
                                              const float* __restrict__ W2, unsigned short* __restrict__ Wt) {
  int i = blockIdx.x * 256 + threadIdx.x;   // 0 .. 3*16384
  int l = i >> 14;
  int r = i & 16383;
  int nn = r >> 7, kk = r & 127;
  const float* W = (l == 0) ? W0 : (l == 1) ? W1 : W2;
  Wt[i] = (unsigned short)bf16r(W[kk * 128 + nn]);
}

// ---------------- per-layer: GEMM via MFMA bf16 (f32 accumulate, bf16 store) ----------------
// block = 4 waves = 16 rows x 128 cols; wave w -> cols [32w, 32w+32) as two 16x16 tiles.
// A = Zb [m][k] contiguous-8; B = Wt [n][k] contiguous-8 (B^T layout, m90-97 pattern).
// Requires n % 16 == 0 (holds: 50000).

__global__ __launch_bounds__(256) void k_gemm(const unsigned short* __restrict__ Zb,
                                              const unsigned short* __restrict__ Wt,
                                              unsigned short* __restrict__ H, int n) {
  int lane = threadIdx.x & 63;
  int wid  = threadIdx.x >> 6;
  int row0 = blockIdx.x * 16;
  int r  = lane & 15;
  int kg = lane >> 4;
  int c0 = wid * 32;
  const size_t abase = (size_t)(row0 + r) * 128 + kg * 8;
  const size_t b0base = (size_t)(c0 + r) * 128 + kg * 8;
  const size_t b1base = (size_t)(c0 + 16 + r) * 128 + kg * 8;
  f32x4 acc0 = {0.f, 0.f, 0.f, 0.f};
  f32x4 acc1 = {0.f, 0.f, 0.f, 0.f};
#pragma unroll
  for (int k0 = 0; k0 < 128; k0 += 32) {
    bf16x8 a  = *(const bf16x8*)&Zb[abase + k0];
    bf16x8 b0 = *(const bf16x8*)&Wt[b0base + k0];
    bf16x8 b1 = *(const bf16x8*)&Wt[b1base + k0];
    acc0 = __builtin_amdgcn_mfma_f32_16x16x32_bf16(a, b0, acc0, 0, 0, 0);
    acc1 = __builtin_amdgcn_mfma_f32_16x16x32_bf16(a, b1, acc1, 0, 0, 0);
  }
  // C/D: col = lane&15, row = (lane>>4)*4 + reg   [m89-verified]
  int orow = row0 + kg * 4;
#pragma unroll
  for (int j = 0; j < 4; ++j) {
    H[(size_t)(orow + j) * 128 + c0 + r]      = (unsigned short)bf16r(acc0[j]);
    H[(size_t)(orow + j) * 128 + c0 + 16 + r] = (unsigned short)bf16r(acc1[j]);
  }
}

// ---------------- per-layer: aggregation + bias + relu ----------------
// one 64-lane wave per node; lane holds 1 dword = 2 bf16 features; 4-edge unroll.
// outb != nullptr -> write bf16 (hidden layers); else f32 nontemporal to outf.

__global__ __launch_bounds__(256) void k_agg(const unsigned* __restrict__ Hb, const int* __restrict__ rowptr,
                                             const float2* __restrict__ csr, const float* __restrict__ dis,
                                             const float* __restrict__ bias, unsigned* __restrict__ outb,
                                             float* __restrict__ outf, int n) {
  int node = __builtin_amdgcn_readfirstlane(blockIdx.x * 4 + (threadIdx.x >> 6));
  if (node >= n) return;
  int lane = threadIdx.x & 63;
  float ax = 0.f, ay = 0.f;
  int e = rowptr[node];
  const int end = rowptr[node + 1];
  for (; e + 4 <= end; e += 4) {
    float2 r0 = csr[e];
    float2 r1 = csr[e + 1];
    float2 r2 = csr[e + 2];
    float2 r3 = csr[e + 3];
    unsigned g0 = Hb[(size_t)__float_as_int(r0.x) * 64 + lane];
    unsigned g1 = Hb[(size_t)__float_as_int(r1.x) * 64 + lane];
    unsigned g2 = Hb[(size_t)__float_as_int(r2.x) * 64 + lane];
    unsigned g3 = Hb[(size_t)__float_as_int(r3.x) * 64 + lane];
    ax = fmaf(__uint_as_float(g0 << 16), r0.y, ax); ay = fmaf(__uint_as_float(g0 & 0xffff0000u), r0.y, ay);
    ax = fmaf(__uint_as_float(g1 << 16), r1.y, ax); ay = fmaf(__uint_as_float(g1 & 0xffff0000u), r1.y, ay);
    ax = fmaf(__uint_as_float(g2 << 16), r2.y, ax); ay = fmaf(__uint_as_float(g2 & 0xffff0000u), r2.y, ay);
    ax = fmaf(__uint_as_float(g3 << 16), r3.y, ax); ay = fmaf(__uint_as_float(g3 & 0xffff0000u), r3.y, ay);
  }
  for (; e < end; ++e) {
    float2 r0 = csr[e];
    unsigned g0 = Hb[(size_t)__float_as_int(r0.x) * 64 + lane];
    ax = fmaf(__uint_as_float(g0 << 16), r0.y, ax); ay = fmaf(__uint_as_float(g0 & 0xffff0000u), r0.y, ay);
  }
  float dn = dis[node];
  float sn = dn * dn;
  unsigned hv = Hb[(size_t)node * 64 + lane];
  float hvx = __uint_as_float(hv << 16);
  float hvy = __uint_as_float(hv & 0xffff0000u);
  float2 bv = ((const float2*)bias)[lane];
  float ox = fmaxf(fmaf(dn, ax, fmaf(sn, hvx, bv.x)), 0.f);
  float oy = fmaxf(fmaf(dn, ay, fmaf(sn, hvy, bv.y)), 0.f);
  if (outb) {
    outb[(size_t)node * 64 + lane] = bf16r(ox) | (bf16r(oy) << 16);
  } else {
    f2v o; o.x = ox; o.y = oy;
    __builtin_nontemporal_store(o, (f2v*)outf + (size_t)node * 64 + lane);
  }
}

// ---------------- host ----------------

extern "C" void kernel_launch(void* const* d_in, const int* in_sizes, int n_in,
                              void* d_out, int out_size, void* d_ws, size_t ws_size,
                              hipStream_t stream) {
  const float* x  = (const float*)d_in[0];
  const int*   ei = (const int*)d_in[1];   // int32: [2, E] row-major
  const float* ew = (const float*)d_in[2];
  const float* W0 = (const float*)d_in[3];
  const float* W1 = (const float*)d_in[5];
  const float* W2 = (const float*)d_in[7];
  const float* bl[3] = {(const float*)d_in[4], (const float*)d_in[6], (const float*)d_in[8]};

  const int n = in_sizes[0] / D;
  const int E = in_sizes[1] / 2;
  const int* src = ei;
  const int* dst = ei + E;

  char* p = (char*)d_ws;
  unsigned short* Zb      = (unsigned short*)p; p += (size_t)n * D * 2;  // also holds xb for layer 0
  unsigned short* H       = (unsigned short*)p; p += (size_t)n * D * 2;
  float*          dis     = (float*)p;          p += (size_t)n * 4;
  int*            cnt     = (int*)p;            p += (size_t)n * 4;
  int*            rowptr  = (int*)p;            p += (size_t)(n + 1) * 4;
  int*            bsum    = (int*)p;            p += 256 * 4;
  int*            boff    = (int*)p;            p += 256 * 4;
  int*            p_local = (int*)p;            p += (size_t)E * 4;
  float2*         csr     = (float2*)p;         p += (size_t)E * 8;
  unsigned short* Wt      = (unsigned short*)p; p += 3 * 16384 * 2;
  (void)ws_size; (void)n_in;

  const int gb = (n + 255) / 256;
  const int ge = (E + 255) / 256;

  // CSR build + norm precompute
  k_init<<<gb, 256, 0, stream>>>(cnt, n);
  k_rank<<<ge, 256, 0, stream>>>(dst, cnt, p_local, E);
  k_blocksum<<<gb, 256, 0, stream>>>(cnt, bsum, n);
  k_scanb<<<1, 256, 0, stream>>>(bsum, boff, gb);
  k_scanc<<<gb, 256, 0, stream>>>(cnt, boff, rowptr, n, E);
  k_scatter<<<ge, 256, 0, stream>>>(src, dst, ew, rowptr, p_local, csr, E);
  k_degdis<<<(n + 3) / 4, 256, 0, stream>>>(csr, rowptr, dis, n);
  k_norm<<<ge, 256, 0, stream>>>(csr, dis, E);

  // converts
  const int total4 = n * D / 4;
  k_cvt<<<(total4 + 255) / 256, 256, 0, stream>>>(x, Zb, total4);
  k_cvtw<<<(3 * 16384 + 255) / 256, 256, 0, stream>>>(W0, W1, W2, Wt);

  float* outp = (float*)d_out;
  for (int l = 0; l < 3; ++l) {
    k_gemm<<<n / 16, 256, 0, stream>>>(Zb, Wt + l * 16384, H, n);
    unsigned* ob = (l == 2) ? nullptr : (unsigned*)Zb;
    k_agg<<<(n + 3) / 4, 256, 0, stream>>>((const unsigned*)H, rowptr, csr, dis, bl[l], ob, outp, n);
  }
}

// Round 8
// 250.579 us; speedup vs baseline: 1.4530x; 1.0287x over previous
//
#include <hip/hip_runtime.h>

#define D 128

typedef float f2v __attribute__((ext_vector_type(2)));
typedef short bf16x8 __attribute__((ext_vector_type(8)));
typedef float f32x4 __attribute__((ext_vector_type(4)));

// bf16 round-to-nearest-even
__device__ __forceinline__ unsigned bf16r(float f) {
  unsigned u = __float_as_uint(f);
  return (u + 0x7fffu + ((u >> 16) & 1u)) >> 16;
}

// ---------------- precompute ----------------

__global__ __launch_bounds__(256) void k_init(int* __restrict__ cnt, int n) {
  int i = blockIdx.x * 256 + threadIdx.x;
  if (i < n) cnt[i] = 0;
}

// fused: [0,GR) rank atomics | [GR,GR+GC) x->bf16 cvt | [GR+GC,..) W cvt+transpose
__global__ __launch_bounds__(256) void k_pre1(const int* __restrict__ dst, int* __restrict__ cnt,
                                              int* __restrict__ p_local, int E, int GR,
                                              const float* __restrict__ X, unsigned short* __restrict__ Xb,
                                              int total4, int GC,
                                              const float* __restrict__ W0, const float* __restrict__ W1,
                                              const float* __restrict__ W2, unsigned short* __restrict__ Wt) {
  int b = blockIdx.x;
  int tid = threadIdx.x;
  if (b < GR) {
    int e = b * 256 + tid;
    if (e < E) p_local[e] = atomicAdd(&cnt[dst[e]], 1);
  } else if (b < GR + GC) {
    int i = (b - GR) * 256 + tid;
    if (i < total4) {
      float4 v = ((const float4*)X)[i];
      ushort4 o;
      o.x = (unsigned short)bf16r(v.x);
      o.y = (unsigned short)bf16r(v.y);
      o.z = (unsigned short)bf16r(v.z);
      o.w = (unsigned short)bf16r(v.w);
      ((ushort4*)Xb)[i] = o;
    }
  } else {
    int i = (b - GR - GC) * 256 + tid;
    if (i < 3 * 16384) {
      int l = i >> 14;
      int r = i & 16383;
      int nn = r >> 7, kk = r & 127;
      const float* W = (l == 0) ? W0 : (l == 1) ? W1 : W2;
      Wt[i] = (unsigned short)bf16r(W[kk * 128 + nn]);
    }
  }
}

__global__ __launch_bounds__(256) void k_blocksum(const int* __restrict__ cnt, int* __restrict__ bsum, int n) {
  int i = blockIdx.x * 256 + threadIdx.x;
  int v = (i < n) ? cnt[i] : 0;
#pragma unroll
  for (int off = 32; off > 0; off >>= 1) v += __shfl_down(v, off);
  __shared__ int ws[4];
  if ((threadIdx.x & 63) == 0) ws[threadIdx.x >> 6] = v;
  __syncthreads();
  if (threadIdx.x == 0) bsum[blockIdx.x] = ws[0] + ws[1] + ws[2] + ws[3];
}

__global__ __launch_bounds__(256) void k_scanb(const int* __restrict__ bsum, int* __restrict__ boff, int nb) {
  __shared__ int s[256];
  int t = threadIdx.x;
  int v = (t < nb) ? bsum[t] : 0;
  s[t] = v;
  __syncthreads();
#pragma unroll
  for (int off = 1; off < 256; off <<= 1) {
    int u = (t >= off) ? s[t - off] : 0;
    __syncthreads();
    s[t] += u;
    __syncthreads();
  }
  if (t < nb) boff[t] = s[t] - v;  // exclusive
}

__global__ __launch_bounds__(256) void k_scanc(const int* __restrict__ cnt, const int* __restrict__ boff,
                                               int* __restrict__ rowptr, int n, int Etot) {
  __shared__ int s[256];
  int t = threadIdx.x;
  int i = blockIdx.x * 256 + t;
  int v = (i < n) ? cnt[i] : 0;
  s[t] = v;
  __syncthreads();
#pragma unroll
  for (int off = 1; off < 256; off <<= 1) {
    int u = (t >= off) ? s[t - off] : 0;
    __syncthreads();
    s[t] += u;
    __syncthreads();
  }
  int ex = s[t] - v + boff[blockIdx.x];
  if (i < n) rowptr[i] = ex;
  if (i == 0) rowptr[n] = Etot;
}

// fused: [0,GG) layer-0 MFMA GEMM | [GG,..) atomic-free CSR scatter
__global__ __launch_bounds__(256) void k_pre2(const unsigned short* __restrict__ Zb,
                                              const unsigned short* __restrict__ Wt,
                                              unsigned short* __restrict__ H, int n, int GG,
                                              const int* __restrict__ src, const int* __restrict__ dst,
                                              const float* __restrict__ ew, const int* __restrict__ rowptr,
                                              const int* __restrict__ p_local, float2* __restrict__ csr, int E) {
  int b = blockIdx.x;
  if (b < GG) {
    int lane = threadIdx.x & 63;
    int wid  = threadIdx.x >> 6;
    int row0 = b * 16;
    int r  = lane & 15;
    int kg = lane >> 4;
    int c0 = wid * 32;
    const size_t abase  = (size_t)(row0 + r) * 128 + kg * 8;
    const size_t b0base = (size_t)(c0 + r) * 128 + kg * 8;
    const size_t b1base = (size_t)(c0 + 16 + r) * 128 + kg * 8;
    f32x4 acc0 = {0.f, 0.f, 0.f, 0.f};
    f32x4 acc1 = {0.f, 0.f, 0.f, 0.f};
#pragma unroll
    for (int k0 = 0; k0 < 128; k0 += 32) {
      bf16x8 a  = *(const bf16x8*)&Zb[abase + k0];
      bf16x8 b0 = *(const bf16x8*)&Wt[b0base + k0];
      bf16x8 b1 = *(const bf16x8*)&Wt[b1base + k0];
      acc0 = __builtin_amdgcn_mfma_f32_16x16x32_bf16(a, b0, acc0, 0, 0, 0);
      acc1 = __builtin_amdgcn_mfma_f32_16x16x32_bf16(a, b1, acc1, 0, 0, 0);
    }
    int orow = row0 + kg * 4;
#pragma unroll
    for (int j = 0; j < 4; ++j) {
      H[(size_t)(orow + j) * 128 + c0 + r]      = (unsigned short)bf16r(acc0[j]);
      H[(size_t)(orow + j) * 128 + c0 + 16 + r] = (unsigned short)bf16r(acc1[j]);
    }
  } else {
    int e = (b - GG) * 256 + threadIdx.x;
    if (e < E) {
      int d = dst[e];
      int pos = rowptr[d] + p_local[e];
      float2 rec;
      rec.x = __int_as_float(src[e]);
      rec.y = ew[e];
      csr[pos] = rec;
    }
  }
}

// wave per node: deg = 1 + sum(ew over row); dis = rsqrt(deg)
__global__ __launch_bounds__(256) void k_degdis(const float2* __restrict__ csr, const int* __restrict__ rowptr,
                                                float* __restrict__ dis, int n) {
  int node = blockIdx.x * 4 + (threadIdx.x >> 6);
  if (node >= n) return;
  int lane = threadIdx.x & 63;
  int beg = rowptr[node], end = rowptr[node + 1];
  float s = 0.f;
  for (int e = beg + lane; e < end; e += 64) s += csr[e].y;
#pragma unroll
  for (int off = 32; off > 0; off >>= 1) s += __shfl_down(s, off);
  if (lane == 0) {
    float dg = 1.0f + s;
    dis[node] = dg > 0.f ? rsqrtf(dg) : 0.f;
  }
}

// ---------------- per-layer: GEMM via MFMA bf16 (layers 1,2) ----------------

__global__ __launch_bounds__(256) void k_gemm(const unsigned short* __restrict__ Zb,
                                              const unsigned short* __restrict__ Wt,
                                              unsigned short* __restrict__ H, int n) {
  int lane = threadIdx.x & 63;
  int wid  = threadIdx.x >> 6;
  int row0 = blockIdx.x * 16;
  int r  = lane & 15;
  int kg = lane >> 4;
  int c0 = wid * 32;
  const size_t abase  = (size_t)(row0 + r) * 128 + kg * 8;
  const size_t b0base = (size_t)(c0 + r) * 128 + kg * 8;
  const size_t b1base = (size_t)(c0 + 16 + r) * 128 + kg * 8;
  f32x4 acc0 = {0.f, 0.f, 0.f, 0.f};
  f32x4 acc1 = {0.f, 0.f, 0.f, 0.f};
#pragma unroll
  for (int k0 = 0; k0 < 128; k0 += 32) {
    bf16x8 a  = *(const bf16x8*)&Zb[abase + k0];
    bf16x8 b0 = *(const bf16x8*)&Wt[b0base + k0];
    bf16x8 b1 = *(const bf16x8*)&Wt[b1base + k0];
    acc0 = __builtin_amdgcn_mfma_f32_16x16x32_bf16(a, b0, acc0, 0, 0, 0);
    acc1 = __builtin_amdgcn_mfma_f32_16x16x32_bf16(a, b1, acc1, 0, 0, 0);
  }
  int orow = row0 + kg * 4;
#pragma unroll
  for (int j = 0; j < 4; ++j) {
    H[(size_t)(orow + j) * 128 + c0 + r]      = (unsigned short)bf16r(acc0[j]);
    H[(size_t)(orow + j) * 128 + c0 + 16 + r] = (unsigned short)bf16r(acc1[j]);
  }
}

// ---------------- per-layer: aggregation + bias + relu ----------------
// one 64-lane wave per node; dis[src] folded on the fly (dis is L2-resident).
// out = dis[n]*sum_e (dis[src]*ew)*h[src] + dis[n]^2*h[n] + b, relu

__global__ __launch_bounds__(256) void k_agg(const unsigned* __restrict__ Hb, const int* __restrict__ rowptr,
                                             const f2v* __restrict__ csr, const float* __restrict__ dis,
                                             const float* __restrict__ bias, unsigned* __restrict__ outb,
                                             float* __restrict__ outf, int n) {
  int node = __builtin_amdgcn_readfirstlane(blockIdx.x * 4 + (threadIdx.x >> 6));
  if (node >= n) return;
  int lane = threadIdx.x & 63;
  float ax = 0.f, ay = 0.f;
  int e = rowptr[node];
  const int end = rowptr[node + 1];
  for (; e + 4 <= end; e += 4) {
    f2v r0 = __builtin_nontemporal_load(&csr[e]);
    f2v r1 = __builtin_nontemporal_load(&csr[e + 1]);
    f2v r2 = __builtin_nontemporal_load(&csr[e + 2]);
    f2v r3 = __builtin_nontemporal_load(&csr[e + 3]);
    int s0 = __float_as_int(r0.x);
    int s1 = __float_as_int(r1.x);
    int s2 = __float_as_int(r2.x);
    int s3 = __float_as_int(r3.x);
    float w0 = r0.y * dis[s0];
    float w1 = r1.y * dis[s1];
    float w2 = r2.y * dis[s2];
    float w3 = r3.y * dis[s3];
    unsigned g0 = Hb[(size_t)s0 * 64 + lane];
    unsigned g1 = Hb[(size_t)s1 * 64 + lane];
    unsigned g2 = Hb[(size_t)s2 * 64 + lane];
    unsigned g3 = Hb[(size_t)s3 * 64 + lane];
    ax = fmaf(__uint_as_float(g0 << 16), w0, ax); ay = fmaf(__uint_as_float(g0 & 0xffff0000u), w0, ay);
    ax = fmaf(__uint_as_float(g1 << 16), w1, ax); ay = fmaf(__uint_as_float(g1 & 0xffff0000u), w1, ay);
    ax = fmaf(__uint_as_float(g2 << 16), w2, ax); ay = fmaf(__uint_as_float(g2 & 0xffff0000u), w2, ay);
    ax = fmaf(__uint_as_float(g3 << 16), w3, ax); ay = fmaf(__uint_as_float(g3 & 0xffff0000u), w3, ay);
  }
  for (; e < end; ++e) {
    f2v r0 = __builtin_nontemporal_load(&csr[e]);
    int s0 = __float_as_int(r0.x);
    float w0 = r0.y * dis[s0];
    unsigned g0 = Hb[(size_t)s0 * 64 + lane];
    ax = fmaf(__uint_as_float(g0 << 16), w0, ax); ay = fmaf(__uint_as_float(g0 & 0xffff0000u), w0, ay);
  }
  float dn = dis[node];
  float sn = dn * dn;
  unsigned hv = Hb[(size_t)node * 64 + lane];
  float hvx = __uint_as_float(hv << 16);
  float hvy = __uint_as_float(hv & 0xffff0000u);
  float2 bv = ((const float2*)bias)[lane];
  float ox = fmaxf(fmaf(dn, ax, fmaf(sn, hvx, bv.x)), 0.f);
  float oy = fmaxf(fmaf(dn, ay, fmaf(sn, hvy, bv.y)), 0.f);
  if (outb) {
    outb[(size_t)node * 64 + lane] = bf16r(ox) | (bf16r(oy) << 16);
  } else {
    f2v o; o.x = ox; o.y = oy;
    __builtin_nontemporal_store(o, (f2v*)outf + (size_t)node * 64 + lane);
  }
}

// ---------------- host ----------------

extern "C" void kernel_launch(void* const* d_in, const int* in_sizes, int n_in,
                              void* d_out, int out_size, void* d_ws, size_t ws_size,
                              hipStream_t stream) {
  const float* x  = (const float*)d_in[0];
  const int*   ei = (const int*)d_in[1];   // int32: [2, E] row-major
  const float* ew = (const float*)d_in[2];
  const float* W0 = (const float*)d_in[3];
  const float* W1 = (const float*)d_in[5];
  const float* W2 = (const float*)d_in[7];
  const float* bl[3] = {(const float*)d_in[4], (const float*)d_in[6], (const float*)d_in[8]};

  const int n = in_sizes[0] / D;
  const int E = in_sizes[1] / 2;
  const int* src = ei;
  const int* dst = ei + E;

  char* p = (char*)d_ws;
  unsigned short* Zb      = (unsigned short*)p; p += (size_t)n * D * 2;  // xb for layer 0
  unsigned short* H       = (unsigned short*)p; p += (size_t)n * D * 2;
  float*          dis     = (float*)p;          p += (size_t)n * 4;
  int*            cnt     = (int*)p;            p += (size_t)n * 4;
  int*            rowptr  = (int*)p;            p += (size_t)(n + 1) * 4;
  int*            bsum    = (int*)p;            p += 256 * 4;
  int*            boff    = (int*)p;            p += 256 * 4;
  int*            p_local = (int*)p;            p += (size_t)E * 4;
  float2*         csr     = (float2*)p;         p += (size_t)E * 8;
  unsigned short* Wt      = (unsigned short*)p; p += 3 * 16384 * 2;
  (void)ws_size; (void)n_in;

  const int gb = (n + 255) / 256;
  const int ge = (E + 255) / 256;          // 3125
  const int total4 = n * D / 4;            // 1.6M
  const int GC = (total4 + 255) / 256;     // 6250
  const int GW = (3 * 16384 + 255) / 256;  // 192
  const int GG = n / 16;                   // 3125 (n % 16 == 0)

  k_init<<<gb, 256, 0, stream>>>(cnt, n);
  k_pre1<<<ge + GC + GW, 256, 0, stream>>>(dst, cnt, p_local, E, ge, x, Zb, total4, GC, W0, W1, W2, Wt);
  k_blocksum<<<gb, 256, 0, stream>>>(cnt, bsum, n);
  k_scanb<<<1, 256, 0, stream>>>(bsum, boff, gb);
  k_scanc<<<gb, 256, 0, stream>>>(cnt, boff, rowptr, n, E);
  k_pre2<<<GG + ge, 256, 0, stream>>>(Zb, Wt, H, n, GG, src, dst, ew, rowptr, p_local, csr, E);
  k_degdis<<<(n + 3) / 4, 256, 0, stream>>>(csr, rowptr, dis, n);

  float* outp = (float*)d_out;
  // layer 0 aggregation (gemm0 already done inside k_pre2)
  k_agg<<<(n + 3) / 4, 256, 0, stream>>>((const unsigned*)H, rowptr, (const f2v*)csr, dis, bl[0], (unsigned*)Zb, outp, n);
  for (int l = 1; l < 3; ++l) {
    k_gemm<<<GG, 256, 0, stream>>>(Zb, Wt + l * 16384, H, n);
    unsigned* ob = (l == 2) ? nullptr : (unsigned*)Zb;
    k_agg<<<(n + 3) / 4, 256, 0, stream>>>((const unsigned*)H, rowptr, (const f2v*)csr, dis, bl[l], ob, outp, n);
  }
}

// Round 9
// 224.274 us; speedup vs baseline: 1.6234x; 1.1173x over previous
//
#include <hip/hip_runtime.h>

#define D 128
#define NB 250    // node buckets
#define BN 200    // nodes per bucket (NB*BN == n == 50000)
#define NBLK 128  // histogram/partition blocks
#define CAP 7168  // LDS-staged edges per bucket (57 KB); global-read fallback past this

typedef float f2v __attribute__((ext_vector_type(2)));
typedef short bf16x8 __attribute__((ext_vector_type(8)));
typedef float f32x4 __attribute__((ext_vector_type(4)));

// bf16 round-to-nearest-even
__device__ __forceinline__ unsigned bf16r(float f) {
  unsigned u = __float_as_uint(f);
  return (u + 0x7fffu + ((u >> 16) & 1u)) >> 16;
}

// ---------------- pass A + converts ----------------
// blocks [0,NBLK): LDS bucket histogram of dst -> M[blk][NB]
// blocks [NBLK,NBLK+GC): x -> bf16
// rest: W -> bf16 transposed [n][k]

__global__ __launch_bounds__(256) void k_pre1(const int* __restrict__ dst, int* __restrict__ M, int E,
                                              const float* __restrict__ X, unsigned short* __restrict__ Xb,
                                              int total4, int GC,
                                              const float* __restrict__ W0, const float* __restrict__ W1,
                                              const float* __restrict__ W2, unsigned short* __restrict__ Wt) {
  __shared__ int lh[NB];
  int b = blockIdx.x;
  int tid = threadIdx.x;
  if (b < NBLK) {
    for (int i = tid; i < NB; i += 256) lh[i] = 0;
    __syncthreads();
    const int EPB = (E + NBLK - 1) / NBLK;
    int e0 = b * EPB;
    int e1 = min(e0 + EPB, E);
    for (int e = e0 + tid; e < e1; e += 256) atomicAdd(&lh[dst[e] / BN], 1);
    __syncthreads();
    for (int i = tid; i < NB; i += 256) M[b * NB + i] = lh[i];
  } else if (b < NBLK + GC) {
    int i = (b - NBLK) * 256 + tid;
    if (i < total4) {
      float4 v = ((const float4*)X)[i];
      ushort4 o;
      o.x = (unsigned short)bf16r(v.x);
      o.y = (unsigned short)bf16r(v.y);
      o.z = (unsigned short)bf16r(v.z);
      o.w = (unsigned short)bf16r(v.w);
      ((ushort4*)Xb)[i] = o;
    }
  } else {
    int i = (b - NBLK - GC) * 256 + tid;
    if (i < 3 * 16384) {
      int l = i >> 14;
      int r = i & 16383;
      int nn = r >> 7, kk = r & 127;
      const float* W = (l == 0) ? W0 : (l == 1) ? W1 : W2;
      Wt[i] = (unsigned short)bf16r(W[kk * 128 + nn]);
    }
  }
}

// ---------------- matrix scan: bucket bases + per-(blk,bucket) bases ----------------
// single block, 256 threads; thread t owns bucket column t (t < NB)

__global__ __launch_bounds__(256) void k_mscan(int* __restrict__ M, int* __restrict__ bbase, int Etot) {
  __shared__ int s[256];
  int t = threadIdx.x;
  int v = 0;
  if (t < NB) {
    for (int blk = 0; blk < NBLK; ++blk) v += M[blk * NB + t];
  }
  s[t] = v;
  __syncthreads();
#pragma unroll
  for (int off = 1; off < 256; off <<= 1) {
    int u = (t >= off) ? s[t - off] : 0;
    __syncthreads();
    s[t] += u;
    __syncthreads();
  }
  int ex = s[t] - v;  // exclusive bucket base
  if (t < NB) {
    bbase[t] = ex;
    int run = ex;
    for (int blk = 0; blk < NBLK; ++blk) {
      int c = M[blk * NB + t];
      M[blk * NB + t] = run;
      run += c;
    }
  }
  if (t == 0) bbase[NB] = Etot;
}

// ---------------- pass B + layer-0 GEMM ----------------
// blocks [0,GG): MFMA gemm0 ; blocks [GG,GG+NBLK): partition edges into buckets

__global__ __launch_bounds__(256) void k_pre2(const unsigned short* __restrict__ Zb,
                                              const unsigned short* __restrict__ Wt,
                                              unsigned short* __restrict__ H, int n, int GG,
                                              const int* __restrict__ src, const int* __restrict__ dst,
                                              const float* __restrict__ ew, const int* __restrict__ M,
                                              uint2* __restrict__ part, int E) {
  __shared__ int lcur[NB];
  int b = blockIdx.x;
  if (b < GG) {
    int lane = threadIdx.x & 63;
    int wid  = threadIdx.x >> 6;
    int row0 = b * 16;
    int r  = lane & 15;
    int kg = lane >> 4;
    int c0 = wid * 32;
    const size_t abase  = (size_t)(row0 + r) * 128 + kg * 8;
    const size_t b0base = (size_t)(c0 + r) * 128 + kg * 8;
    const size_t b1base = (size_t)(c0 + 16 + r) * 128 + kg * 8;
    f32x4 acc0 = {0.f, 0.f, 0.f, 0.f};
    f32x4 acc1 = {0.f, 0.f, 0.f, 0.f};
#pragma unroll
    for (int k0 = 0; k0 < 128; k0 += 32) {
      bf16x8 a  = *(const bf16x8*)&Zb[abase + k0];
      bf16x8 b0 = *(const bf16x8*)&Wt[b0base + k0];
      bf16x8 b1 = *(const bf16x8*)&Wt[b1base + k0];
      acc0 = __builtin_amdgcn_mfma_f32_16x16x32_bf16(a, b0, acc0, 0, 0, 0);
      acc1 = __builtin_amdgcn_mfma_f32_16x16x32_bf16(a, b1, acc1, 0, 0, 0);
    }
    int orow = row0 + kg * 4;
#pragma unroll
    for (int j = 0; j < 4; ++j) {
      H[(size_t)(orow + j) * 128 + c0 + r]      = (unsigned short)bf16r(acc0[j]);
      H[(size_t)(orow + j) * 128 + c0 + 16 + r] = (unsigned short)bf16r(acc1[j]);
    }
  } else {
    int blk = b - GG;
    int tid = threadIdx.x;
    for (int i = tid; i < NB; i += 256) lcur[i] = M[blk * NB + i];
    __syncthreads();
    const int EPB = (E + NBLK - 1) / NBLK;
    int e0 = blk * EPB;
    int e1 = min(e0 + EPB, E);
    for (int e = e0 + tid; e < e1; e += 256) {
      int d = dst[e];
      int bkt = d / BN;
      int dlow = d - bkt * BN;
      int p = atomicAdd(&lcur[bkt], 1);
      uint2 rec;
      rec.x = (unsigned)src[e] | ((unsigned)dlow << 24);
      rec.y = __float_as_uint(ew[e]);
      part[p] = rec;
    }
  }
}

// ---------------- pass C: per-bucket counting sort -> csr, rowptr, dis ----------------
// one block per bucket; edges staged in LDS (fallback to global reads past CAP)

__global__ __launch_bounds__(256) void k_bsort(const uint2* __restrict__ part, const int* __restrict__ bbase,
                                               uint2* __restrict__ csr, int* __restrict__ rowptr,
                                               float* __restrict__ dis, int n, int E) {
  __shared__ uint2 stage[CAP];
  __shared__ int lh[BN];
  __shared__ float ldeg[BN];
  __shared__ int s[256];
  int b = blockIdx.x;
  int tid = threadIdx.x;
  int base = bbase[b];
  int cnt = bbase[b + 1] - base;
  for (int i = tid; i < BN; i += 256) { lh[i] = 0; ldeg[i] = 0.f; }
  __syncthreads();
  for (int i = tid; i < cnt; i += 256) {
    uint2 r = part[base + i];
    if (i < CAP) stage[i] = r;
    int dlow = r.x >> 24;
    atomicAdd(&lh[dlow], 1);
    atomicAdd(&ldeg[dlow], __uint_as_float(r.y));
  }
  __syncthreads();
  int v = (tid < BN) ? lh[tid] : 0;
  s[tid] = v;
  __syncthreads();
#pragma unroll
  for (int off = 1; off < 256; off <<= 1) {
    int u = (tid >= off) ? s[tid - off] : 0;
    __syncthreads();
    s[tid] += u;
    __syncthreads();
  }
  int ex = s[tid] - v;  // exclusive node offset within bucket
  if (tid < BN) {
    lh[tid] = ex;  // becomes running cursor
    int node = b * BN + tid;
    rowptr[node] = base + ex;
    dis[node] = rsqrtf(1.0f + ldeg[tid]);
  }
  if (b == 0 && tid == 0) rowptr[n] = E;
  __syncthreads();
  for (int i = tid; i < cnt; i += 256) {
    uint2 r = (i < CAP) ? stage[i] : part[base + i];
    int dlow = r.x >> 24;
    int p = atomicAdd(&lh[dlow], 1);
    uint2 o;
    o.x = r.x & 0x00FFFFFFu;
    o.y = r.y;
    csr[base + p] = o;
  }
}

// ---------------- per-layer: GEMM via MFMA bf16 (layers 1,2) ----------------

__global__ __launch_bounds__(256) void k_gemm(const unsigned short* __restrict__ Zb,
                                              const unsigned short* __restrict__ Wt,
                                              unsigned short* __restrict__ H, int n) {
  int lane = threadIdx.x & 63;
  int wid  = threadIdx.x >> 6;
  int row0 = blockIdx.x * 16;
  int r  = lane & 15;
  int kg = lane >> 4;
  int c0 = wid * 32;
  const size_t abase  = (size_t)(row0 + r) * 128 + kg * 8;
  const size_t b0base = (size_t)(c0 + r) * 128 + kg * 8;
  const size_t b1base = (size_t)(c0 + 16 + r) * 128 + kg * 8;
  f32x4 acc0 = {0.f, 0.f, 0.f, 0.f};
  f32x4 acc1 = {0.f, 0.f, 0.f, 0.f};
#pragma unroll
  for (int k0 = 0; k0 < 128; k0 += 32) {
    bf16x8 a  = *(const bf16x8*)&Zb[abase + k0];
    bf16x8 b0 = *(const bf16x8*)&Wt[b0base + k0];
    bf16x8 b1 = *(const bf16x8*)&Wt[b1base + k0];
    acc0 = __builtin_amdgcn_mfma_f32_16x16x32_bf16(a, b0, acc0, 0, 0, 0);
    acc1 = __builtin_amdgcn_mfma_f32_16x16x32_bf16(a, b1, acc1, 0, 0, 0);
  }
  int orow = row0 + kg * 4;
#pragma unroll
  for (int j = 0; j < 4; ++j) {
    H[(size_t)(orow + j) * 128 + c0 + r]      = (unsigned short)bf16r(acc0[j]);
    H[(size_t)(orow + j) * 128 + c0 + 16 + r] = (unsigned short)bf16r(acc1[j]);
  }
}

// ---------------- per-layer: aggregation + bias + relu ----------------
// one 64-lane wave per node; dis[src] folded on the fly (dis is L2-resident).
// out = dis[n]*sum_e (dis[src]*ew)*h[src] + dis[n]^2*h[n] + b, relu

__global__ __launch_bounds__(256) void k_agg(const unsigned* __restrict__ Hb, const int* __restrict__ rowptr,
                                             const f2v* __restrict__ csr, const float* __restrict__ dis,
                                             const float* __restrict__ bias, unsigned* __restrict__ outb,
                                             float* __restrict__ outf, int n) {
  int node = __builtin_amdgcn_readfirstlane(blockIdx.x * 4 + (threadIdx.x >> 6));
  if (node >= n) return;
  int lane = threadIdx.x & 63;
  float ax = 0.f, ay = 0.f;
  int e = rowptr[node];
  const int end = rowptr[node + 1];
  for (; e + 4 <= end; e += 4) {
    f2v r0 = __builtin_nontemporal_load(&csr[e]);
    f2v r1 = __builtin_nontemporal_load(&csr[e + 1]);
    f2v r2 = __builtin_nontemporal_load(&csr[e + 2]);
    f2v r3 = __builtin_nontemporal_load(&csr[e + 3]);
    int s0 = __float_as_int(r0.x);
    int s1 = __float_as_int(r1.x);
    int s2 = __float_as_int(r2.x);
    int s3 = __float_as_int(r3.x);
    float w0 = r0.y * dis[s0];
    float w1 = r1.y * dis[s1];
    float w2 = r2.y * dis[s2];
    float w3 = r3.y * dis[s3];
    unsigned g0 = Hb[(size_t)s0 * 64 + lane];
    unsigned g1 = Hb[(size_t)s1 * 64 + lane];
    unsigned g2 = Hb[(size_t)s2 * 64 + lane];
    unsigned g3 = Hb[(size_t)s3 * 64 + lane];
    ax = fmaf(__uint_as_float(g0 << 16), w0, ax); ay = fmaf(__uint_as_float(g0 & 0xffff0000u), w0, ay);
    ax = fmaf(__uint_as_float(g1 << 16), w1, ax); ay = fmaf(__uint_as_float(g1 & 0xffff0000u), w1, ay);
    ax = fmaf(__uint_as_float(g2 << 16), w2, ax); ay = fmaf(__uint_as_float(g2 & 0xffff0000u), w2, ay);
    ax = fmaf(__uint_as_float(g3 << 16), w3, ax); ay = fmaf(__uint_as_float(g3 & 0xffff0000u), w3, ay);
  }
  for (; e < end; ++e) {
    f2v r0 = __builtin_nontemporal_load(&csr[e]);
    int s0 = __float_as_int(r0.x);
    float w0 = r0.y * dis[s0];
    unsigned g0 = Hb[(size_t)s0 * 64 + lane];
    ax = fmaf(__uint_as_float(g0 << 16), w0, ax); ay = fmaf(__uint_as_float(g0 & 0xffff0000u), w0, ay);
  }
  float dn = dis[node];
  float sn = dn * dn;
  unsigned hv = Hb[(size_t)node * 64 + lane];
  float hvx = __uint_as_float(hv << 16);
  float hvy = __uint_as_float(hv & 0xffff0000u);
  float2 bv = ((const float2*)bias)[lane];
  float ox = fmaxf(fmaf(dn, ax, fmaf(sn, hvx, bv.x)), 0.f);
  float oy = fmaxf(fmaf(dn, ay, fmaf(sn, hvy, bv.y)), 0.f);
  if (outb) {
    outb[(size_t)node * 64 + lane] = bf16r(ox) | (bf16r(oy) << 16);
  } else {
    f2v o; o.x = ox; o.y = oy;
    __builtin_nontemporal_store(o, (f2v*)outf + (size_t)node * 64 + lane);
  }
}

// ---------------- host ----------------

extern "C" void kernel_launch(void* const* d_in, const int* in_sizes, int n_in,
                              void* d_out, int out_size, void* d_ws, size_t ws_size,
                              hipStream_t stream) {
  const float* x  = (const float*)d_in[0];
  const int*   ei = (const int*)d_in[1];   // int32: [2, E] row-major
  const float* ew = (const float*)d_in[2];
  const float* W0 = (const float*)d_in[3];
  const float* W1 = (const float*)d_in[5];
  const float* W2 = (const float*)d_in[7];
  const float* bl[3] = {(const float*)d_in[4], (const float*)d_in[6], (const float*)d_in[8]};

  const int n = in_sizes[0] / D;   // 50000 == NB*BN
  const int E = in_sizes[1] / 2;
  const int* src = ei;
  const int* dst = ei + E;

  char* p = (char*)d_ws;
  unsigned short* Zb     = (unsigned short*)p; p += (size_t)n * D * 2;  // xb for layer 0
  unsigned short* H      = (unsigned short*)p; p += (size_t)n * D * 2;
  float*          dis    = (float*)p;          p += (size_t)n * 4;
  int*            rowptr = (int*)p;            p += (size_t)(n + 1) * 4;
  int*            M      = (int*)p;            p += (size_t)NBLK * NB * 4;
  int*            bbase  = (int*)p;            p += (size_t)(NB + 1) * 4;
  uint2*          part   = (uint2*)p;          p += (size_t)E * 8;
  uint2*          csr    = (uint2*)p;          p += (size_t)E * 8;
  unsigned short* Wt     = (unsigned short*)p; p += 3 * 16384 * 2;
  (void)ws_size; (void)n_in;

  const int total4 = n * D / 4;            // 1.6M
  const int GC = (total4 + 255) / 256;     // 6250
  const int GW = (3 * 16384 + 255) / 256;  // 192
  const int GG = n / 16;                   // 3125 (n % 16 == 0)

  k_pre1<<<NBLK + GC + GW, 256, 0, stream>>>(dst, M, E, x, Zb, total4, GC, W0, W1, W2, Wt);
  k_mscan<<<1, 256, 0, stream>>>(M, bbase, E);
  k_pre2<<<GG + NBLK, 256, 0, stream>>>(Zb, Wt, H, n, GG, src, dst, ew, M, part, E);
  k_bsort<<<NB, 256, 0, stream>>>(part, bbase, csr, rowptr, dis, n, E);

  float* outp = (float*)d_out;
  // layer 0 aggregation (gemm0 already done inside k_pre2)
  k_agg<<<(n + 3) / 4, 256, 0, stream>>>((const unsigned*)H, rowptr, (const f2v*)csr, dis, bl[0], (unsigned*)Zb, outp, n);
  for (int l = 1; l < 3; ++l) {
    k_gemm<<<GG, 256, 0, stream>>>(Zb, Wt + l * 16384, H, n);
    unsigned* ob = (l == 2) ? nullptr : (unsigned*)Zb;
    k_agg<<<(n + 3) / 4, 256, 0, stream>>>((const unsigned*)H, rowptr, (const f2v*)csr, dis, bl[l], ob, outp, n);
  }
}